// Round 1
// baseline (10632.163 us; speedup 1.0000x reference)
//
#include <hip/hip_runtime.h>
#include <hip/hip_bf16.h>

#define S_LEN 512
#define B_SZ  256
#define F_SZ  256
#define H_SZ  1024
#define NGRP  16
#define WPG   16     // workgroups per batch-group (j-tiles)
#define KEEP  0.5f

typedef float f32x4 __attribute__((ext_vector_type(4)));
typedef short s16x8 __attribute__((ext_vector_type(8)));

static __device__ __forceinline__ short f2bf(float f) {
    unsigned u = __builtin_bit_cast(unsigned, f);
    unsigned r = u + 0x7fffu + ((u >> 16) & 1u);   // RNE to bf16
    return (short)(r >> 16);
}

static __device__ __forceinline__ s16x8 pack8(f32x4 lo, f32x4 hi, float s) {
    s16x8 r;
#pragma unroll
    for (int i = 0; i < 4; ++i) { r[i] = f2bf(lo[i] * s); r[i + 4] = f2bf(hi[i] * s); }
    return r;
}

static __device__ __forceinline__ float fast_tanh(float v) {
    float e = __expf(2.0f * v);
    return (e - 1.0f) / (e + 1.0f);
}

// Grid: 256 WGs = 16 batch-groups x 16 j-tiles. Block: 256 threads (4 waves).
// Wave w of WG (g,t) computes C[b0..b0+16, j0..j0+16] with j0 = t*64 + w*16.
// W_h2h j-slice held in registers as bf16 B-fragments (no LDS, no per-step W reads).
__global__ __launch_bounds__(256, 1) void rnn_fused(
    const float* __restrict__ x, const float* __restrict__ Wi,
    const float* __restrict__ bias, const float* __restrict__ Wh,
    const float* __restrict__ h0, float* __restrict__ out,
    short* __restrict__ hbuf, int* __restrict__ ctr)
{
    const int bid  = blockIdx.x;
    const int g    = bid >> 4;     // batch-group 0..15
    const int t    = bid & 15;     // j-tile 0..15
    const int tid  = threadIdx.x;
    const int wave = tid >> 6;
    const int lane = tid & 63;
    const int ln   = lane & 15;    // col/row-in-tile index
    const int lk   = lane >> 4;    // k-group 0..3

    const int b0 = g * 16;
    const int j  = t * 64 + wave * 16 + ln;

    // --- preload weights into registers as MFMA B-fragments (bf16) ---
    // B-frag for 16x16x32: lane holds col=(lane&15) -> j, k=(lane>>4)*8 + [0..8)
    s16x8 wh[32];
#pragma unroll
    for (int ks = 0; ks < 32; ++ks) {
        const float* p = Wh + j * H_SZ + ks * 32 + lk * 8;
        wh[ks] = pack8(*(const f32x4*)p, *(const f32x4*)(p + 4), 1.0f);
    }
    s16x8 wif[8];
#pragma unroll
    for (int kf = 0; kf < 8; ++kf) {
        const float* p = Wi + j * F_SZ + kf * 32 + lk * 8;
        wif[kf] = pack8(*(const f32x4*)p, *(const f32x4*)(p + 4), 1.0f);
    }
    const float bj = bias[j];

    const int arow = b0 + ln;              // A-fragment row (batch index)
    const int hoff = arow * H_SZ + lk * 8; // element offset into h buffer
    int* const myctr = ctr + g * S_LEN;

#pragma unroll 1
    for (int s = 0; s < S_LEN; ++s) {
        f32x4 acc = { bj, bj, bj, bj };

        // --- input projection (independent of h: overlaps barrier latency) ---
        const float* xp = x + ((size_t)s * B_SZ + arow) * F_SZ + lk * 8;
#pragma unroll
        for (int kf = 0; kf < 8; ++kf) {
            s16x8 a = pack8(*(const f32x4*)(xp + kf * 32),
                            *(const f32x4*)(xp + kf * 32 + 4), 1.0f);
            acc = __builtin_amdgcn_mfma_f32_16x16x32_bf16(a, wif[kf], acc, 0, 0, 0);
        }

        if (s > 0) {
            // wait for all 16 WGs of this group to publish h(s-1)
            if (tid == 0) {
                while (__hip_atomic_load(myctr + (s - 1), __ATOMIC_RELAXED,
                                         __HIP_MEMORY_SCOPE_AGENT) < WPG)
                    __builtin_amdgcn_s_sleep(1);
                __threadfence();   // acquire: invalidate L1/L2 before h reads
            }
            __syncthreads();
            const short* hp = hbuf + ((s - 1) & 1) * (B_SZ * H_SZ) + hoff;
#pragma unroll
            for (int ks = 0; ks < 32; ++ks) {
                s16x8 a = *(const s16x8*)(hp + ks * 32);  // h already scaled by KEEP
                acc = __builtin_amdgcn_mfma_f32_16x16x32_bf16(a, wh[ks], acc, 0, 0, 0);
            }
        } else {
            // step 0: h0 broadcast across batch -> same fragment for all rows
#pragma unroll
            for (int ks = 0; ks < 32; ++ks) {
                const float* p = h0 + ks * 32 + lk * 8;
                s16x8 a = pack8(*(const f32x4*)p, *(const f32x4*)(p + 4), KEEP);
                acc = __builtin_amdgcn_mfma_f32_16x16x32_bf16(a, wh[ks], acc, 0, 0, 0);
            }
        }

        // C/D layout: col = lane&15 (=j), row = (lane>>4)*4 + reg (=batch)
        const int crow = b0 + lk * 4;
        if (s < S_LEN - 1) {
            short* op = hbuf + (s & 1) * (B_SZ * H_SZ);
#pragma unroll
            for (int r = 0; r < 4; ++r)
                op[(crow + r) * H_SZ + j] = f2bf(KEEP * fast_tanh(acc[r]));
            __syncthreads();  // drains vmcnt for all waves before signal
            if (tid == 0) { __threadfence(); atomicAdd(myctr + s, 1); }
        } else {
            // final step: write fp32 hidden straight to output
#pragma unroll
            for (int r = 0; r < 4; ++r)
                out[(crow + r) * H_SZ + j] = fast_tanh(acc[r]);
        }
    }
}

extern "C" void kernel_launch(void* const* d_in, const int* in_sizes, int n_in,
                              void* d_out, int out_size, void* d_ws, size_t ws_size,
                              hipStream_t stream) {
    const float* x  = (const float*)d_in[0];
    const float* Wi = (const float*)d_in[1];
    const float* bi = (const float*)d_in[2];
    const float* Wh = (const float*)d_in[3];
    const float* h0 = (const float*)d_in[4];
    float* out = (float*)d_out;

    int*   ctr  = (int*)d_ws;                          // 16*512*4 = 32 KB
    short* hbuf = (short*)((char*)d_ws + (64 << 10));  // 2 x 256x1024 bf16 = 1 MB

    // counters MUST be zero every call (harness replays without re-poisoning)
    hipMemsetAsync(d_ws, 0, NGRP * S_LEN * sizeof(int), stream);
    rnn_fused<<<dim3(NGRP * WPG), dim3(256), 0, stream>>>(x, Wi, bi, Wh, h0, out, hbuf, ctr);
}

// Round 2
// 4302.281 us; speedup vs baseline: 2.4713x; 2.4713x over previous
//
#include <hip/hip_runtime.h>
#include <hip/hip_bf16.h>

#define S_LEN 512
#define B_SZ  256
#define F_SZ  256
#define H_SZ  1024
#define NGRP  16
#define WPG   16     // workgroups per batch-group (j-tiles)
#define KEEP  0.5f

typedef float f32x4 __attribute__((ext_vector_type(4)));
typedef short s16x8 __attribute__((ext_vector_type(8)));

static __device__ __forceinline__ short f2bf(float f) {
    unsigned u = __builtin_bit_cast(unsigned, f);
    unsigned r = u + 0x7fffu + ((u >> 16) & 1u);   // RNE to bf16
    return (short)(r >> 16);
}

static __device__ __forceinline__ s16x8 pack8(f32x4 lo, f32x4 hi, float s) {
    s16x8 r;
#pragma unroll
    for (int i = 0; i < 4; ++i) { r[i] = f2bf(lo[i] * s); r[i + 4] = f2bf(hi[i] * s); }
    return r;
}

static __device__ __forceinline__ float fast_tanh(float v) {
    float e = __expf(2.0f * v);
    return (e - 1.0f) / (e + 1.0f);
}

// All cross-WG data goes through the memory-side L3 (coherent across XCDs):
// relaxed system-scope ops compile to global_* sc0 sc1 — NO L2 writeback/inv.
#define SYS_LD(p)    __hip_atomic_load((p), __ATOMIC_RELAXED, __HIP_MEMORY_SCOPE_SYSTEM)
#define SYS_ST(p,v)  __hip_atomic_store((p), (v), __ATOMIC_RELAXED, __HIP_MEMORY_SCOPE_SYSTEM)

// Grid: 256 WGs = 16 batch-groups x 16 j-tiles. Block: 256 threads (4 waves).
// Wave w of WG (g,t) computes C[b0..b0+16, j0..j0+16], j0 = t*64 + w*16.
// W_h2h j-slice in registers. Per-step sync: 64 monotonic per-wave flags per
// group at L3; each wave polls independently (one flag per lane + __all).
__global__ __launch_bounds__(256, 1) void rnn_fused(
    const float* __restrict__ x, const float* __restrict__ Wi,
    const float* __restrict__ bias, const float* __restrict__ Wh,
    const float* __restrict__ h0, float* __restrict__ out,
    short* __restrict__ hbuf, int* __restrict__ flags)
{
    __shared__ char h_lds[32768];  // 16 rows x 1024 bf16, XOR-swizzled
    const int bid  = blockIdx.x;
    const int g    = bid >> 4;     // batch-group 0..15
    const int t    = bid & 15;     // j-tile 0..15
    const int tid  = threadIdx.x;
    const int wave = tid >> 6;
    const int lane = tid & 63;
    const int ln   = lane & 15;
    const int lk   = lane >> 4;

    const int b0   = g * 16;
    const int j    = t * 64 + wave * 16 + ln;
    const int wIdx = t * 4 + wave;             // wave id within group (0..63)

    // --- preload weights into registers as MFMA B-fragments (bf16) ---
    s16x8 wh[32];
#pragma unroll
    for (int ks = 0; ks < 32; ++ks) {
        const float* p = Wh + j * H_SZ + ks * 32 + lk * 8;
        wh[ks] = pack8(*(const f32x4*)p, *(const f32x4*)(p + 4), 1.0f);
    }
    s16x8 wif[8];
#pragma unroll
    for (int kf = 0; kf < 8; ++kf) {
        const float* p = Wi + j * F_SZ + kf * 32 + lk * 8;
        wif[kf] = pack8(*(const f32x4*)p, *(const f32x4*)(p + 4), 1.0f);
    }
    const float bj = bias[j];

    const int arow = b0 + ln;
    int* const gflag = flags + g * 64;

#pragma unroll 1
    for (int s = 0; s < S_LEN; ++s) {
        f32x4 acc = { bj, bj, bj, bj };

        // --- input projection (no h dependency: overlaps producers' tails) ---
        const float* xp = x + ((size_t)s * B_SZ + arow) * F_SZ + lk * 8;
#pragma unroll
        for (int kf = 0; kf < 8; ++kf) {
            s16x8 a = pack8(*(const f32x4*)(xp + kf * 32),
                            *(const f32x4*)(xp + kf * 32 + 4), 1.0f);
            acc = __builtin_amdgcn_mfma_f32_16x16x32_bf16(a, wif[kf], acc, 0, 0, 0);
        }

        if (s > 0) {
            // wait until all 64 waves of this group published h(s-1)
            for (;;) {
                int v = SYS_LD(gflag + lane);
                if (__all(v >= s)) break;
                __builtin_amdgcn_s_sleep(1);
            }
            asm volatile("" ::: "memory");  // keep loads below the poll

            // cooperative WG load of the 32 KB h-slice L3 -> LDS (swizzled)
            const long* hsrc = (const long*)(hbuf + ((s - 1) & 1) * (B_SZ * H_SZ)
                                             + b0 * H_SZ);
#pragma unroll
            for (int k2 = 0; k2 < 16; ++k2) {           // k2 == local batch row
                long v = SYS_LD(hsrc + k2 * 256 + tid);
                int boff = k2 * 2048 + tid * 8;
                *(long*)(h_lds + (boff ^ ((k2 & 7) << 4))) = v;
            }
            __syncthreads();

#pragma unroll
            for (int ks = 0; ks < 32; ++ks) {
                int roff = ln * 2048 + ks * 64 + lk * 16;
                s16x8 a = *(const s16x8*)(h_lds + (roff ^ ((ln & 7) << 4)));
                acc = __builtin_amdgcn_mfma_f32_16x16x32_bf16(a, wh[ks], acc, 0, 0, 0);
            }
        } else {
            // step 0: h0 broadcast across batch -> same fragment for all rows
#pragma unroll
            for (int ks = 0; ks < 32; ++ks) {
                const float* p = h0 + ks * 32 + lk * 8;
                s16x8 a = pack8(*(const f32x4*)p, *(const f32x4*)(p + 4), KEEP);
                acc = __builtin_amdgcn_mfma_f32_16x16x32_bf16(a, wh[ks], acc, 0, 0, 0);
            }
        }

        // C/D layout: col = lane&15 (=j), row = (lane>>4)*4 + reg (=batch)
        const int crow = b0 + lk * 4;
        if (s < S_LEN - 1) {
            short* op = hbuf + (s & 1) * (B_SZ * H_SZ);
#pragma unroll
            for (int r = 0; r < 4; ++r)
                SYS_ST(&op[(crow + r) * H_SZ + j], f2bf(KEEP * fast_tanh(acc[r])));
            asm volatile("s_waitcnt vmcnt(0)" ::: "memory");  // h at L3 before flag
            if (lane == 0) SYS_ST(gflag + wIdx, s + 1);       // monotonic flag
        } else {
            // final step: write fp32 hidden straight to output
#pragma unroll
            for (int r = 0; r < 4; ++r)
                out[(crow + r) * H_SZ + j] = fast_tanh(acc[r]);
        }
    }
}

extern "C" void kernel_launch(void* const* d_in, const int* in_sizes, int n_in,
                              void* d_out, int out_size, void* d_ws, size_t ws_size,
                              hipStream_t stream) {
    const float* x  = (const float*)d_in[0];
    const float* Wi = (const float*)d_in[1];
    const float* bi = (const float*)d_in[2];
    const float* Wh = (const float*)d_in[3];
    const float* h0 = (const float*)d_in[4];
    float* out = (float*)d_out;

    int*   flags = (int*)d_ws;                          // 16*64*4 = 4 KB
    short* hbuf  = (short*)((char*)d_ws + (64 << 10));  // 2 x 256x1024 bf16 = 1 MB

    // flags MUST be zero every call (harness replays without re-poisoning)
    hipMemsetAsync(d_ws, 0, NGRP * 64 * sizeof(int), stream);
    rnn_fused<<<dim3(NGRP * WPG), dim3(256), 0, stream>>>(x, Wi, bi, Wh, h0, out, hbuf, flags);
}

// Round 4
// 3318.319 us; speedup vs baseline: 3.2041x; 1.2965x over previous
//
#include <hip/hip_runtime.h>
#include <hip/hip_bf16.h>

#define S_LEN 512
#define B_SZ  256
#define F_SZ  256
#define H_SZ  1024
#define BH    (B_SZ * H_SZ)
#define KEEP  0.5f

typedef float f32x4 __attribute__((ext_vector_type(4)));
typedef short s16x8 __attribute__((ext_vector_type(8)));

static __device__ __forceinline__ short f2bf(float f) {
    unsigned u = __builtin_bit_cast(unsigned, f);
    unsigned r = u + 0x7fffu + ((u >> 16) & 1u);   // RNE to bf16
    return (short)(r >> 16);
}

static __device__ __forceinline__ s16x8 pack8(f32x4 lo, f32x4 hi, float s) {
    s16x8 r;
#pragma unroll
    for (int i = 0; i < 4; ++i) { r[i] = f2bf(lo[i] * s); r[i + 4] = f2bf(hi[i] * s); }
    return r;
}

static __device__ __forceinline__ float fast_tanh(float v) {
    float e = __expf(2.0f * v);
    return (e - 1.0f) / (e + 1.0f);
}

#define SYS_LD(p)   __hip_atomic_load((p), __ATOMIC_RELAXED, __HIP_MEMORY_SCOPE_SYSTEM)
#define SYS_ST(p,v) __hip_atomic_store((p), (v), __ATOMIC_RELAXED, __HIP_MEMORY_SCOPE_SYSTEM)

// h data load: PURE -> sc0 (bypass L1, hit XCD-local L2); mixed -> sc0 sc1 (L3).
template<int PURE>
static __device__ __forceinline__ s16x8 ldh(const short* p) {
    s16x8 v;
    if constexpr (PURE)
        asm volatile("global_load_dwordx4 %0, %1, off sc0" : "=v"(v) : "v"(p));
    else
        asm volatile("global_load_dwordx4 %0, %1, off sc0 sc1" : "=v"(v) : "v"(p));
    return v;
}

template<int PURE>
static __device__ __forceinline__ int ldflag(const int* p) {
    int v;
    if constexpr (PURE)
        asm volatile("global_load_dword %0, %1, off sc0\n\ts_waitcnt vmcnt(0)"
                     : "=v"(v) : "v"(p) : "memory");
    else
        asm volatile("global_load_dword %0, %1, off sc0 sc1\n\ts_waitcnt vmcnt(0)"
                     : "=v"(v) : "v"(p) : "memory");
    return v;
}

#define WAIT_SB(N) do { asm volatile("s_waitcnt vmcnt(" #N ")" ::: "memory"); \
                        __builtin_amdgcn_sched_barrier(0); } while (0)

// The full per-step loop, instantiated for PURE (same-XCD L2 comms) and mixed (L3).
template<int PURE>
static __device__ __forceinline__ void step_loop(
    const float* __restrict__ x, const float* __restrict__ h0,
    float* __restrict__ out, short* __restrict__ hbuf, int* __restrict__ flags,
    const s16x8 (&wh)[32], const s16x8 (&wif)[8], float bj,
    int g, int b0, int j, int wIdx, int arow, int hoff, int lane, int lk, int dmask)
{
#pragma unroll 1
    for (int s = 0; s < S_LEN; ++s) {
        f32x4 acc = { bj, bj, bj, bj };

        // --- input projection (no h dependency: overlaps producers' tails) ---
        const float* xp = x + ((size_t)s * B_SZ + arow) * F_SZ + lk * 8;
#pragma unroll
        for (int kf = 0; kf < 8; ++kf) {
            s16x8 a = pack8(*(const f32x4*)(xp + kf * 32),
                            *(const f32x4*)(xp + kf * 32 + 4), 1.0f);
            acc = __builtin_amdgcn_mfma_f32_16x16x32_bf16(a, wif[kf], acc, 0, 0, 0);
        }

        if (s > 0) {
            // wait until all 64 waves of this group published h(s-1)
            const int* fp = flags + g * 64 + lane;
            int it = 0;
            for (;;) {
                int v = ldflag<PURE>(fp);
                if (__all(v >= s)) break;
                if ((++it & 31) == 31) {  // liveness: atomics always bypass L1
                    v = __hip_atomic_fetch_add((int*)fp, 0, __ATOMIC_RELAXED,
                                               __HIP_MEMORY_SCOPE_AGENT);
                    if (__all(v >= s)) break;
                }
                __builtin_amdgcn_s_sleep(1);
            }

            const short* hb = hbuf + (size_t)((s - 1) & dmask) * BH + hoff;
            s16x8 A0[8], A1[8];
#pragma unroll
            for (int i = 0; i < 8; ++i) A0[i] = ldh<PURE>(hb + i * 32);
#pragma unroll
            for (int i = 0; i < 8; ++i) A1[i] = ldh<PURE>(hb + 256 + i * 32);
            WAIT_SB(8);
#pragma unroll
            for (int i = 0; i < 8; ++i)
                acc = __builtin_amdgcn_mfma_f32_16x16x32_bf16(A0[i], wh[i], acc, 0, 0, 0);
#pragma unroll
            for (int i = 0; i < 8; ++i) A0[i] = ldh<PURE>(hb + 512 + i * 32);
            WAIT_SB(8);
#pragma unroll
            for (int i = 0; i < 8; ++i)
                acc = __builtin_amdgcn_mfma_f32_16x16x32_bf16(A1[i], wh[8 + i], acc, 0, 0, 0);
#pragma unroll
            for (int i = 0; i < 8; ++i) A1[i] = ldh<PURE>(hb + 768 + i * 32);
            WAIT_SB(8);
#pragma unroll
            for (int i = 0; i < 8; ++i)
                acc = __builtin_amdgcn_mfma_f32_16x16x32_bf16(A0[i], wh[16 + i], acc, 0, 0, 0);
            WAIT_SB(0);
#pragma unroll
            for (int i = 0; i < 8; ++i)
                acc = __builtin_amdgcn_mfma_f32_16x16x32_bf16(A1[i], wh[24 + i], acc, 0, 0, 0);
        } else {
            // step 0: h0 broadcast across batch -> same fragment for all rows
#pragma unroll
            for (int ks = 0; ks < 32; ++ks) {
                const float* p = h0 + ks * 32 + lk * 8;
                s16x8 a = pack8(*(const f32x4*)p, *(const f32x4*)(p + 4), KEEP);
                acc = __builtin_amdgcn_mfma_f32_16x16x32_bf16(a, wh[ks], acc, 0, 0, 0);
            }
        }

        // C/D layout: col = lane&15 (=j), row = (lane>>4)*4 + reg (=batch)
        const int crow = b0 + lk * 4;
        if (s < S_LEN - 1) {
            short* op = hbuf + (size_t)(s & dmask) * BH;
            if constexpr (PURE) {
#pragma unroll
                for (int r = 0; r < 4; ++r)
                    op[(crow + r) * H_SZ + j] = f2bf(KEEP * fast_tanh(acc[r]));
            } else {
#pragma unroll
                for (int r = 0; r < 4; ++r)
                    SYS_ST(&op[(crow + r) * H_SZ + j], f2bf(KEEP * fast_tanh(acc[r])));
            }
            asm volatile("s_waitcnt vmcnt(0)" ::: "memory");  // h visible before flag
            if (lane == 0) {
                int* flp = flags + g * 64 + wIdx;
                int fv = s + 1;
                if constexpr (PURE)
                    asm volatile("global_store_dword %0, %1, off sc0"
                                 :: "v"(flp), "v"(fv) : "memory");
                else
                    SYS_ST(flp, fv);
            }
        } else {
            // final step: write fp32 hidden straight to output
#pragma unroll
            for (int r = 0; r < 4; ++r)
                out[(crow + r) * H_SZ + j] = fast_tanh(acc[r]);
        }
    }
}

// Grid: 256 WGs x 256 thr. role remap clusters each 16-WG group onto one XCD
// (verified at runtime via HW_REG_XCC_ID roster; fallback = system-scope L3).
__global__ __launch_bounds__(256, 1) void rnn_fused(
    const float* __restrict__ x, const float* __restrict__ Wi,
    const float* __restrict__ bias, const float* __restrict__ Wh,
    const float* __restrict__ h0, float* __restrict__ out,
    short* __restrict__ hbuf, int* __restrict__ roster, int* __restrict__ flags,
    int dmask)
{
    __shared__ int sh_pure;
    const int bid  = blockIdx.x;
    const int role = ((bid & 7) << 5) | (bid >> 3);   // same-XCD groups under RR lore
    const int g    = role >> 4;     // batch-group 0..15
    const int t    = role & 15;     // j-tile 0..15
    const int tid  = threadIdx.x;
    const int wave = tid >> 6;
    const int lane = tid & 63;
    const int ln   = lane & 15;
    const int lk   = lane >> 4;

    int xcc;
    asm volatile("s_getreg_b32 %0, hwreg(HW_REG_XCC_ID)" : "=s"(xcc));
    xcc &= 7;

    if (tid == 0) SYS_ST(&roster[role], xcc + 1);     // publish my XCD (one-time)
    if (tid < 16) {                                   // verify group co-residency
        const int* rp = roster + g * 16 + tid;
        int v;
        do { v = SYS_LD(rp); if (v) break; __builtin_amdgcn_s_sleep(1); } while (1);
        int p = __all(v == __shfl(v, 0));
        if (tid == 0) sh_pure = p;
    }
    __syncthreads();
    const int pure = sh_pure;

    const int b0 = g * 16;
    const int j  = t * 64 + wave * 16 + ln;
    const int wIdx = t * 4 + wave;
    const int arow = b0 + ln;
    const int hoff = arow * H_SZ + lk * 8;

    // --- W_h2h / W_i2h j-slices live in registers as MFMA B-fragments ---
    s16x8 wh[32];
#pragma unroll
    for (int ks = 0; ks < 32; ++ks) {
        const float* p = Wh + j * H_SZ + ks * 32 + lk * 8;
        wh[ks] = pack8(*(const f32x4*)p, *(const f32x4*)(p + 4), 1.0f);
    }
    s16x8 wif[8];
#pragma unroll
    for (int kf = 0; kf < 8; ++kf) {
        const float* p = Wi + j * F_SZ + kf * 32 + lk * 8;
        wif[kf] = pack8(*(const f32x4*)p, *(const f32x4*)(p + 4), 1.0f);
    }
    const float bj = bias[j];

    if (pure)
        step_loop<1>(x, h0, out, hbuf, flags, wh, wif, bj,
                     g, b0, j, wIdx, arow, hoff, lane, lk, dmask);
    else
        step_loop<0>(x, h0, out, hbuf, flags, wh, wif, bj,
                     g, b0, j, wIdx, arow, hoff, lane, lk, dmask);
}

extern "C" void kernel_launch(void* const* d_in, const int* in_sizes, int n_in,
                              void* d_out, int out_size, void* d_ws, size_t ws_size,
                              hipStream_t stream) {
    const float* x  = (const float*)d_in[0];
    const float* Wi = (const float*)d_in[1];
    const float* bi = (const float*)d_in[2];
    const float* Wh = (const float*)d_in[3];
    const float* h0 = (const float*)d_in[4];
    float* out = (float*)d_out;

    int*   roster = (int*)d_ws;                          // 256 ints
    int*   flags  = (int*)d_ws + 256;                    // 16*64 ints
    short* hbuf   = (short*)((char*)d_ws + (64 << 10));  // depth x 512 KB bf16

    // 4-deep rotation if workspace allows (L1-freshness belt+suspenders), else 2.
    const size_t need4 = (64u << 10) + 4u * ((size_t)BH * 2);
    const int dmask = (ws_size >= need4) ? 3 : 1;

    // roster + flags MUST be zero every call (graph replays don't re-poison)
    (void)hipMemsetAsync(d_ws, 0, (256 + 16 * 64) * sizeof(int), stream);
    rnn_fused<<<dim3(256), dim3(256), 0, stream>>>(x, Wi, bi, Wh, h0, out,
                                                   hbuf, roster, flags, dmask);
}